// Round 4
// baseline (56.288 us; speedup 1.0000x reference)
//
#include <hip/hip_runtime.h>
#include <hip/hip_fp16.h>

// Output = abs(column 63 after both transforms). Only W1 row 63 and
// P = W2r+W2i, Q = W2r-W2i are needed. Memory-bound: streams x once.
//
// Phase A: Y[b,n] = sum_c x[b,n,c] . W1row63[c]  (row 0 = passthrough of
//   x[b,0,63]); 16 lanes per row (4 complexes each), 4 rows per wave-iter,
//   4-step butterfly. Row 0's 512 B are skipped except the final 16 B
//   (-1.5% HBM traffic).
// Phase B: out[b,m] = | sum_n Yr[n]*P[m,n] + Yi[n]*Q[m,n] |, P/Q packed
//   half2 in LDS (18.7 KiB/block -> 8 blocks/CU, 32 waves/CU).

typedef float vf4 __attribute__((ext_vector_type(4)));  // native vec for nt builtins

static __device__ __forceinline__ vf4 nt_load4(const float* p) {
    return __builtin_nontemporal_load((const vf4*)p);
}

__global__ __launch_bounds__(256, 8)
void cnet_kernel(const float* __restrict__ x,
                 const float* __restrict__ W1r,
                 const float* __restrict__ W1i,
                 const float* __restrict__ W2r,
                 const float* __restrict__ W2i,
                 float* __restrict__ out) {
    __shared__ __half2 PQt[64 * 65];   // [n][m] = (P[m,n], Q[m,n]); +1 pad keeps
                                       // the transposed staging writes conflict-free
    __shared__ float2  YW[4][64];      // per-wave phase-A result

    const int tid  = threadIdx.x;
    const int w    = tid >> 6;    // wave id 0..3
    const int lane = tid & 63;
    const int lg   = lane >> 4;   // row within quad (0..3)
    const int li   = lane & 15;   // position within row: complexes 4li..4li+3

    // Stage P/Q packed fp16, transposed. Coalesced W2 reads; writes at
    // dword stride 65 -> bank = (65*idx)%32 = idx%32, conflict-free.
    for (int idx = tid; idx < 4096; idx += 256) {
        const int m = idx >> 6;
        const int n = idx & 63;
        const float wr = W2r[idx];
        const float wi = W2i[idx];
        PQt[n * 65 + m] = __halves2half2(__float2half_rn(wr + wi),
                                         __float2half_rn(wr - wi));
    }

    // W1 row 63 coefficients for this lane's 4 columns (4li..4li+3).
    const float4 A0 = ((const float4*)(W1r + 63 * 64))[li];
    const float4 B0 = ((const float4*)(W1i + 63 * 64))[li];

    const int b = blockIdx.x * 4 + w;                     // one batch per wave
    const float* xp = x + (size_t)b * 8192;               // 8192 floats/batch

    __syncthreads();

    // ---- Phase A, q = 0 peeled: row 0 is passthrough, skip its bytes ----
    {
        if (lane == 15) {
            const vf4 v = nt_load4(xp + 31 * 4);          // cols 62,63 of row 0
            YW[w][0] = make_float2(v.z, v.w);
        }
        if (lane >= 16) {                                 // rows 1..3, full transform
            const vf4 u = nt_load4(xp + 8 * lane);
            const vf4 v = nt_load4(xp + 8 * lane + 4);
            float pr = u.x*A0.x - u.y*B0.x + u.z*A0.y - u.w*B0.y
                     + v.x*A0.z - v.y*B0.z + v.z*A0.w - v.w*B0.w;
            float pi = u.y*A0.x + u.x*B0.x + u.w*A0.y + u.z*B0.y
                     + v.y*A0.z + v.x*B0.z + v.w*A0.w + v.z*B0.w;
            #pragma unroll
            for (int msk = 1; msk < 16; msk <<= 1) {      // reduce within 16-lane groups
                pr += __shfl_xor(pr, msk);
                pi += __shfl_xor(pi, msk);
            }
            if (li == 0) YW[w][lg] = make_float2(pr, pi); // n = lg = 1,2,3
        }
    }

    // ---- Phase A, q = 1..15 ----
    #pragma unroll 5
    for (int q = 1; q < 16; ++q) {
        const vf4 u = nt_load4(xp + q * 512 + 8 * lane);
        const vf4 v = nt_load4(xp + q * 512 + 8 * lane + 4);
        float pr = u.x*A0.x - u.y*B0.x + u.z*A0.y - u.w*B0.y
                 + v.x*A0.z - v.y*B0.z + v.z*A0.w - v.w*B0.w;
        float pi = u.y*A0.x + u.x*B0.x + u.w*A0.y + u.z*B0.y
                 + v.y*A0.z + v.x*B0.z + v.w*A0.w + v.z*B0.w;
        #pragma unroll
        for (int msk = 1; msk < 16; msk <<= 1) {
            pr += __shfl_xor(pr, msk);
            pi += __shfl_xor(pi, msk);
        }
        if (li == 0) YW[w][q * 4 + lg] = make_float2(pr, pi);
    }
    // YW is written and read by the same wave only -> no barrier needed.

    // ---- Phase B: lane = output index m ----
    float acc = 0.f;
    #pragma unroll 8
    for (int n = 0; n < 64; ++n) {
        const float2  y  = YW[w][n];            // broadcast read
        const __half2 pq = PQt[n * 65 + lane];  // conflict-free b32 read
        acc += y.x * __low2float(pq) + y.y * __high2float(pq);
    }
    __builtin_nontemporal_store(fabsf(acc), out + (size_t)b * 64 + lane);
}

extern "C" void kernel_launch(void* const* d_in, const int* in_sizes, int n_in,
                              void* d_out, int out_size, void* d_ws, size_t ws_size,
                              hipStream_t stream) {
    const float* x   = (const float*)d_in[0];
    const float* W1r = (const float*)d_in[1];
    const float* W1i = (const float*)d_in[2];
    const float* W2r = (const float*)d_in[3];
    const float* W2i = (const float*)d_in[4];
    float* o = (float*)d_out;

    const int B = in_sizes[0] / (64 * 64 * 2);   // 8192 batches
    const int nblocks = B / 4;                   // 1 batch per wave, 4 waves/block
    hipLaunchKernelGGL(cnet_kernel, dim3(nblocks), dim3(256), 0, stream,
                       x, W1r, W1i, W2r, W2i, o);
}

// Round 5
// 47.621 us; speedup vs baseline: 1.1820x; 1.1820x over previous
//
#include <hip/hip_runtime.h>
#include <hip/hip_fp16.h>

// Output = abs(column 63 after both transforms). Only W1 row 63 and
// P = W2r+W2i, Q = W2r-W2i are needed. Memory-bound: streams x (256 MiB) once.
//
// Phase A: Y[b,n] = sum_c x[b,n,c] . W1row63[c]  (row 0 = passthrough of
//   x[b,0,63]). Lane geometry: 8 lanes per row, 8 complexes (64 B) per lane,
//   8 rows per wave-iter, 8 iters; 3-step butterfly (48 shuffles/wave vs 128
//   in the 16-lane variant). Loads: 4 independent float4 per lane per iter,
//   wave footprint 4 KiB contiguous.
// Phase B: out[b,m] = | sum_n Yr[n]*P[m,n] + Yi[n]*Q[m,n] |, P/Q packed
//   half2 in LDS (18.7 KiB/block -> 8 blocks/CU, 32 waves/CU).

typedef float vf4 __attribute__((ext_vector_type(4)));

__global__ __launch_bounds__(256, 8)
void cnet_kernel(const float* __restrict__ x,
                 const float* __restrict__ W1r,
                 const float* __restrict__ W1i,
                 const float* __restrict__ W2r,
                 const float* __restrict__ W2i,
                 float* __restrict__ out) {
    __shared__ __half2 PQt[64 * 65];   // [n][m] = (P[m,n], Q[m,n]); stride 65 dwords
    __shared__ float2  YW[4][64];      // per-wave phase-A result

    const int tid  = threadIdx.x;
    const int w    = tid >> 6;    // wave id 0..3
    const int lane = tid & 63;
    const int lg   = lane >> 3;   // row within octet (0..7)
    const int li   = lane & 7;    // position within row: complexes 8li..8li+7

    // Stage P/Q packed fp16, transposed. Coalesced W2 reads; writes at
    // dword stride 65 -> bank = idx%32, conflict-free.
    for (int idx = tid; idx < 4096; idx += 256) {
        const int m = idx >> 6;
        const int n = idx & 63;
        const float wr = W2r[idx];
        const float wi = W2i[idx];
        PQt[n * 65 + m] = __halves2half2(__float2half_rn(wr + wi),
                                         __float2half_rn(wr - wi));
    }

    // W1 row 63 coefficients for this lane's 8 columns (8li..8li+7).
    const float4 Aa = ((const float4*)(W1r + 63 * 64))[2 * li];
    const float4 Ab = ((const float4*)(W1r + 63 * 64))[2 * li + 1];
    const float4 Ba = ((const float4*)(W1i + 63 * 64))[2 * li];
    const float4 Bb = ((const float4*)(W1i + 63 * 64))[2 * li + 1];

    const int b = blockIdx.x * 4 + w;            // one batch per wave
    const float* xp = x + (size_t)b * 8192;      // 8192 floats/batch

    __syncthreads();

    // ---- Phase A: 8 iters, rows n = q*8 + lg ----
    #pragma unroll 2
    for (int q = 0; q < 8; ++q) {
        const float* base = xp + (q * 8 + lg) * 128 + li * 16;
        const vf4 u0 = *(const vf4*)(base);
        const vf4 u1 = *(const vf4*)(base + 4);
        const vf4 u2 = *(const vf4*)(base + 8);
        const vf4 u3 = *(const vf4*)(base + 12);

        float pr = u0.x*Aa.x - u0.y*Ba.x + u0.z*Aa.y - u0.w*Ba.y
                 + u1.x*Aa.z - u1.y*Ba.z + u1.z*Aa.w - u1.w*Ba.w
                 + u2.x*Ab.x - u2.y*Bb.x + u2.z*Ab.y - u2.w*Bb.y
                 + u3.x*Ab.z - u3.y*Bb.z + u3.z*Ab.w - u3.w*Bb.w;
        float pi = u0.y*Aa.x + u0.x*Ba.x + u0.w*Aa.y + u0.z*Ba.y
                 + u1.y*Aa.z + u1.x*Ba.z + u1.w*Aa.w + u1.z*Ba.w
                 + u2.y*Ab.x + u2.x*Bb.x + u2.w*Ab.y + u2.z*Bb.y
                 + u3.y*Ab.z + u3.x*Bb.z + u3.w*Ab.w + u3.z*Bb.w;

        #pragma unroll
        for (int msk = 1; msk < 8; msk <<= 1) {   // reduce within 8-lane groups
            pr += __shfl_xor(pr, msk);
            pi += __shfl_xor(pi, msk);
        }

        if (q == 0) {
            // Row 0 is NOT transformed: passthrough x[b,0,63,:].
            // Lane 7 (lg=0, li=7) holds complexes 56..63; complex 63 = u3.z/.w.
            if (lane == 7) YW[w][0] = make_float2(u3.z, u3.w);
            if (li == 0 && lg != 0) YW[w][lg] = make_float2(pr, pi);
        } else if (li == 0) {
            YW[w][q * 8 + lg] = make_float2(pr, pi);
        }
    }
    // YW is written and read by the same wave only -> no barrier needed.

    // ---- Phase B: lane = output index m ----
    float acc = 0.f;
    #pragma unroll 8
    for (int n = 0; n < 64; ++n) {
        const float2  y  = YW[w][n];            // broadcast read
        const __half2 pq = PQt[n * 65 + lane];  // conflict-free b32 read
        acc += y.x * __low2float(pq) + y.y * __high2float(pq);
    }
    out[(size_t)b * 64 + lane] = fabsf(acc);
}

extern "C" void kernel_launch(void* const* d_in, const int* in_sizes, int n_in,
                              void* d_out, int out_size, void* d_ws, size_t ws_size,
                              hipStream_t stream) {
    const float* x   = (const float*)d_in[0];
    const float* W1r = (const float*)d_in[1];
    const float* W1i = (const float*)d_in[2];
    const float* W2r = (const float*)d_in[3];
    const float* W2i = (const float*)d_in[4];
    float* o = (float*)d_out;

    const int B = in_sizes[0] / (64 * 64 * 2);   // 8192 batches
    const int nblocks = B / 4;                   // 1 batch per wave, 4 waves/block
    hipLaunchKernelGGL(cnet_kernel, dim3(nblocks), dim3(256), 0, stream,
                       x, W1r, W1i, W2r, W2i, o);
}

// Round 6
// 46.192 us; speedup vs baseline: 1.2186x; 1.0309x over previous
//
#include <hip/hip_runtime.h>
#include <hip/hip_fp16.h>

// Output = abs(column 63 after both transforms). Only W1 row 63 and
// P = W2r+W2i, Q = W2r-W2i are needed. Memory-bound: streams x (256 MiB) once.
//
// This round's single change vs round 5: the 4 waves of a block COOPERATE on
// one batch at a time (wave w owns rows p*32+w*8..+7, pass p=0,1; per-batch
// barrier) so each block emits one tight 32-KiB sequential burst per batch.
// 8 concurrent read streams/CU instead of 32 — tests whether DRAM row-buffer
// locality is what separates 5.68 TB/s from the ~6.3+ TB/s ceiling.
//
// Per-lane math identical to round 5: 8 lanes/row, 8 complexes (64 B)/lane,
// 3-step butterfly; row 0 passthrough of x[b,0,63].
// Phase B: out[b,m] = | sum_n Yr[n]*P[m,n] + Yi[n]*Q[m,n] |, P/Q packed
// half2 in LDS (18.3 KiB/block -> 8 blocks/CU, 32 waves/CU).

typedef float vf4 __attribute__((ext_vector_type(4)));

__global__ __launch_bounds__(256, 8)
void cnet_kernel(const float* __restrict__ x,
                 const float* __restrict__ W1r,
                 const float* __restrict__ W1i,
                 const float* __restrict__ W2r,
                 const float* __restrict__ W2i,
                 float* __restrict__ out) {
    __shared__ __half2 PQt[64 * 65];   // [n][m] = (P[m,n], Q[m,n]); stride 65 dwords
    __shared__ float2  YW[4][64];      // [batch-in-block][n]

    const int tid  = threadIdx.x;
    const int w    = tid >> 6;    // wave id 0..3
    const int lane = tid & 63;
    const int lg   = lane >> 3;   // row within octet (0..7)
    const int li   = lane & 7;    // position within row: complexes 8li..8li+7

    // Stage P/Q packed fp16, transposed. Coalesced W2 reads; writes at
    // dword stride 65 -> bank = idx%32, conflict-free.
    for (int idx = tid; idx < 4096; idx += 256) {
        const int m = idx >> 6;
        const int n = idx & 63;
        const float wr = W2r[idx];
        const float wi = W2i[idx];
        PQt[n * 65 + m] = __halves2half2(__float2half_rn(wr + wi),
                                         __float2half_rn(wr - wi));
    }

    // W1 row 63 coefficients for this lane's 8 columns (8li..8li+7).
    const float4 Aa = ((const float4*)(W1r + 63 * 64))[2 * li];
    const float4 Ab = ((const float4*)(W1r + 63 * 64))[2 * li + 1];
    const float4 Ba = ((const float4*)(W1i + 63 * 64))[2 * li];
    const float4 Bb = ((const float4*)(W1i + 63 * 64))[2 * li + 1];

    __syncthreads();

    // ---- Phase A: block-cooperative, one batch at a time ----
    for (int k = 0; k < 4; ++k) {
        const float* xp = x + (size_t)(blockIdx.x * 4 + k) * 8192;
        #pragma unroll
        for (int p = 0; p < 2; ++p) {
            const int n = p * 32 + w * 8 + lg;             // this lane's row
            const float* base = xp + n * 128 + li * 16;
            const vf4 u0 = *(const vf4*)(base);
            const vf4 u1 = *(const vf4*)(base + 4);
            const vf4 u2 = *(const vf4*)(base + 8);
            const vf4 u3 = *(const vf4*)(base + 12);

            float pr = u0.x*Aa.x - u0.y*Ba.x + u0.z*Aa.y - u0.w*Ba.y
                     + u1.x*Aa.z - u1.y*Ba.z + u1.z*Aa.w - u1.w*Ba.w
                     + u2.x*Ab.x - u2.y*Bb.x + u2.z*Ab.y - u2.w*Bb.y
                     + u3.x*Ab.z - u3.y*Bb.z + u3.z*Ab.w - u3.w*Bb.w;
            float pi = u0.y*Aa.x + u0.x*Ba.x + u0.w*Aa.y + u0.z*Ba.y
                     + u1.y*Aa.z + u1.x*Ba.z + u1.w*Aa.w + u1.z*Ba.w
                     + u2.y*Ab.x + u2.x*Bb.x + u2.w*Ab.y + u2.z*Bb.y
                     + u3.y*Ab.z + u3.x*Bb.z + u3.w*Ab.w + u3.z*Bb.w;

            #pragma unroll
            for (int msk = 1; msk < 8; msk <<= 1) {        // reduce within 8-lane groups
                pr += __shfl_xor(pr, msk);
                pi += __shfl_xor(pi, msk);
            }

            if (p == 0 && w == 0) {
                // Row 0 (n==0) is passthrough x[b,0,63,:]: lane 7 holds
                // complexes 56..63 -> complex 63 = u3.z/.w.
                if (lane == 7) YW[k][0] = make_float2(u3.z, u3.w);
                if (li == 0 && lg != 0) YW[k][lg] = make_float2(pr, pi);
            } else if (li == 0) {
                YW[k][n] = make_float2(pr, pi);
            }
        }
        __syncthreads();   // keep the block's waves in lockstep per batch
    }

    // ---- Phase B: wave w handles batch blockIdx*4+w; lane = output m ----
    float acc = 0.f;
    #pragma unroll 8
    for (int n = 0; n < 64; ++n) {
        const float2  y  = YW[w][n];            // broadcast read
        const __half2 pq = PQt[n * 65 + lane];  // conflict-free b32 read
        acc += y.x * __low2float(pq) + y.y * __high2float(pq);
    }
    out[(size_t)(blockIdx.x * 4 + w) * 64 + lane] = fabsf(acc);
}

extern "C" void kernel_launch(void* const* d_in, const int* in_sizes, int n_in,
                              void* d_out, int out_size, void* d_ws, size_t ws_size,
                              hipStream_t stream) {
    const float* x   = (const float*)d_in[0];
    const float* W1r = (const float*)d_in[1];
    const float* W1i = (const float*)d_in[2];
    const float* W2r = (const float*)d_in[3];
    const float* W2i = (const float*)d_in[4];
    float* o = (float*)d_out;

    const int B = in_sizes[0] / (64 * 64 * 2);   // 8192 batches
    const int nblocks = B / 4;                   // 4 batches per block
    hipLaunchKernelGGL(cnet_kernel, dim3(nblocks), dim3(256), 0, stream,
                       x, W1r, W1i, W2r, W2i, o);
}